// Round 6
// baseline (302.306 us; speedup 1.0000x reference)
//
#include <hip/hip_runtime.h>

// GCNFast: out[b,s,t,d] = relu( sum_j relu(AA[i%64,j%64]*GCW[i,j]) * X[j,b,d] + GCB[i,d] )
// 2-launch: prep writes A2 = relu(AA*GCW) bf16 in FRAGMENT-MAJOR layout [mp][kc][row][8k]
// (A-fragments load global->VGPR directly, coalesced; no LDS for A) + XT bf16 [b*128+d][j].
// GEMM: 128x128 tile, 16x16x32 MFMA (R4 paths, 0 conflicts), single-barrier
// double-buffered sX via global_load_lds dwordx4 + XOR chunk swizzle.

#define NC 64
#define NS 64
#define NT 64
#define DH 128
#define BATCH 16
#define MDIM 4096
#define KDIM 4096
#define TM 128
#define TK 64

typedef __attribute__((ext_vector_type(8))) short short8;
typedef __attribute__((ext_vector_type(4))) float floatx4;

__device__ __forceinline__ unsigned short f2bf(float f) {
    union { float f; unsigned int i; } v; v.f = f;
    return (unsigned short)((v.i + 0x7fffu + ((v.i >> 16) & 1u)) >> 16);
}
__device__ __forceinline__ void async16(const void* g, void* l) {
    __builtin_amdgcn_global_load_lds(
        (const __attribute__((address_space(1))) void*)g,
        (__attribute__((address_space(3))) void*)l, 16, 0, 0);
}

// ---- prep: A2 fragment-major + XT ----
// A-part: 2048 blocks = 32 mp x 64 kcg. Thread (r=tid>>1, kh=tid&1) reads rows
// coalesced (2 threads x 128 B per row), writes 4 short8 chunks kc-major.
// X-part: 1024 blocks, unchanged from R4/R5.
__global__ __launch_bounds__(256)
void prep(const float* __restrict__ aam, const float* __restrict__ gcw,
          const float* __restrict__ hmat,
          unsigned short* __restrict__ A2, unsigned short* __restrict__ XT)
{
    const int bid = blockIdx.x;
    if (bid < 2048) {
        const int mpb = bid >> 6;
        const int kcg = bid & 63;
        const int r   = threadIdx.x >> 1;
        const int kh  = threadIdx.x & 1;
        const size_t gbase = (size_t)(mpb * 128 + r) * KDIM + kcg * 64 + kh * 32;
        floatx4 a[8], w[8];
#pragma unroll
        for (int c = 0; c < 8; ++c) {
            a[c] = *(const floatx4*)(aam + gbase + c * 4);
            w[c] = *(const floatx4*)(gcw + gbase + c * 4);
        }
#pragma unroll
        for (int kc4 = 0; kc4 < 4; ++kc4) {
            short8 p;
#pragma unroll
            for (int e = 0; e < 4; ++e) {
                float v0 = a[kc4 * 2][e] * w[kc4 * 2][e];         v0 = v0 > 0.f ? v0 : 0.f;
                float v1 = a[kc4 * 2 + 1][e] * w[kc4 * 2 + 1][e]; v1 = v1 > 0.f ? v1 : 0.f;
                p[e]     = (short)f2bf(v0);
                p[e + 4] = (short)f2bf(v1);
            }
            const int kc = kcg * 8 + kh * 4 + kc4;
            *(short8*)(A2 + ((size_t)(mpb * 512 + kc) * 128 + r) * 8) = p;
        }
    } else {
        const int xb = bid - 2048;
        const int b = xb >> 6;
        const int t = xb & 63;
        const int d = threadIdx.x & 127;
        const int half = threadIdx.x >> 7;
#pragma unroll
        for (int cc = 0; cc < 4; ++cc) {
            const int c0 = half * 32 + cc * 8;
            short8 p;
#pragma unroll
            for (int e = 0; e < 8; ++e) {
                float v = hmat[(((size_t)b * NC + (c0 + e)) * NT + t) * DH + d];
                p[e] = (short)f2bf(v);
            }
            *(short8*)(XT + ((size_t)(b * DH + d)) * KDIM + t * 64 + c0) = p;
        }
    }
}

// ---- GEMM: af direct from global (A2), sX double-buffered, one barrier/iter ----
__global__ __launch_bounds__(256, 2)
void gemm(const unsigned short* __restrict__ A2,
          const unsigned short* __restrict__ XT,
          const float* __restrict__ gcb,
          float* __restrict__ out)
{
    __shared__ short sX[2][TM * TK];   // two 16 KB X^T tiles, chunk-swizzled

    const int tid = threadIdx.x;
    const int bid = blockIdx.x;
    const int mp  = (bid & 7) * 4 + (bid >> 7);   // m-panel 0..31 (XCD swizzle)
    const int b   = (bid >> 3) & 15;
    const int i0  = mp * TM;

    const int lane = tid & 63;
    const int w    = tid >> 6;
    const int wm = (w >> 1) * 64;
    const int wn = (w & 1) * 64;
    const int l15 = lane & 15;
    const int q   = lane >> 4;

    const int srow = lane >> 3;     // staging row within 8-row group
    const int schk = lane & 7;      // staging 16B chunk within 128B row

    // af global base: addr = A2 + afbase + k0*128 + h*4096 + mi*128  (shorts)
    const size_t afbase = ((size_t)mp * 512 + q) * 1024 + (size_t)(wm + l15) * 8;

    floatx4 acc[4][4];
#pragma unroll
    for (int mi = 0; mi < 4; ++mi)
#pragma unroll
        for (int ni = 0; ni < 4; ++ni)
            acc[mi][ni] = (floatx4){0.f, 0.f, 0.f, 0.f};

    // prologue: stage tile 0 into buf 0
#pragma unroll
    for (int is = 0; is < 4; ++is) {
        const int r  = w * 8 + is * 32 + srow;
        const int kk = (schk ^ (r & 7)) << 3;
        async16(XT + (size_t)(b * DH + r) * KDIM + kk, &sX[0][(w * 8 + is * 32) * TK]);
    }

    int p = 0;
    for (int k0 = 0; k0 < KDIM; k0 += TK) {
        __syncthreads();   // own DMA into buf p drained (vmcnt0), all waves synced

        if (k0 + TK < KDIM) {   // stage next tile into the other buffer
#pragma unroll
            for (int is = 0; is < 4; ++is) {
                const int r  = w * 8 + is * 32 + srow;
                const int kk = k0 + TK + ((schk ^ (r & 7)) << 3);
                async16(XT + (size_t)(b * DH + r) * KDIM + kk,
                        &sX[p ^ 1][(w * 8 + is * 32) * TK]);
            }
        }

        const short* sxp = sX[p];
        const unsigned short* ap = A2 + afbase + (size_t)k0 * 128;

        short8 af[2][4], bf[2][4];
#pragma unroll
        for (int h = 0; h < 2; ++h)
#pragma unroll
            for (int mi = 0; mi < 4; ++mi)
                af[h][mi] = *(const short8*)(ap + h * 4096 + mi * 128);
#pragma unroll
        for (int h = 0; h < 2; ++h)
#pragma unroll
            for (int ni = 0; ni < 4; ++ni) {
                const int row = wn + ni * 16 + l15;
                bf[h][ni] = *(const short8*)&sxp[row * TK + (((h * 4 + q) ^ (l15 & 7)) << 3)];
            }
#pragma unroll
        for (int h = 0; h < 2; ++h)
#pragma unroll
            for (int mi = 0; mi < 4; ++mi)
#pragma unroll
                for (int ni = 0; ni < 4; ++ni)
                    acc[mi][ni] = __builtin_amdgcn_mfma_f32_16x16x32_bf16(
                        af[h][mi], bf[h][ni], acc[mi][ni], 0, 0, 0);
        p ^= 1;
    }

    // epilogue: + GCB, relu, permuted store out[b, s=i&63, t=i>>6, d]
#pragma unroll
    for (int mi = 0; mi < 4; ++mi) {
        const int ibase = i0 + wm + mi * 16 + q * 4;   // C/D: row = q*4 + reg
#pragma unroll
        for (int ni = 0; ni < 4; ++ni) {
            const int d = wn + ni * 16 + l15;          // C/D: col = lane&15
#pragma unroll
            for (int r = 0; r < 4; ++r) {
                const int i = ibase + r;
                float v = acc[mi][ni][r] + gcb[(size_t)i * DH + d];
                v = v > 0.f ? v : 0.f;
                out[(((size_t)b * NS + (i & 63)) * NT + (i >> 6)) * DH + d] = v;
            }
        }
    }
}

// ---- fallback: fused kernel (used only if ws too small) ----
#define APAD 40
#define XPAD 20
__global__ __launch_bounds__(256, 2)
void gcn_fused(const float* __restrict__ hmat, const float* __restrict__ aam,
               const float* __restrict__ gcw, const float* __restrict__ gcb,
               float* __restrict__ out)
{
    __shared__ short sA[TM * APAD];
    __shared__ unsigned int sX[DH * XPAD];
    const int tid = threadIdx.x;
    const int bid = blockIdx.x;
    const int mp  = (bid & 7) * 4 + (bid >> 7);
    const int b   = (bid >> 3) & 15;
    const int i0  = mp * TM;
    const int lane = tid & 63;
    const int wm = ((tid >> 6) >> 1) * 64;
    const int wn = ((tid >> 6) & 1) * 64;
    const int l15 = lane & 15;
    const int q   = lane >> 4;
    floatx4 acc[4][4];
#pragma unroll
    for (int mi = 0; mi < 4; ++mi)
#pragma unroll
        for (int ni = 0; ni < 4; ++ni) acc[mi][ni] = (floatx4){0.f,0.f,0.f,0.f};
    const int ar = tid >> 2, ac = (tid & 3) << 3;
    const int kp = tid >> 4, dg = (tid & 15) << 3;
    const int wkey = (tid & 3) << 2;
    for (int k0 = 0; k0 < KDIM; k0 += 32) {
        const size_t ga0 = (size_t)(i0 + ar) * KDIM + (k0 + ac);
        const size_t ga1 = ga0 + (size_t)64 * KDIM;
        floatx4 aa0a = *(const floatx4*)(aam + ga0), aa0b = *(const floatx4*)(aam + ga0 + 4);
        floatx4 ww0a = *(const floatx4*)(gcw + ga0), ww0b = *(const floatx4*)(gcw + ga0 + 4);
        floatx4 aa1a = *(const floatx4*)(aam + ga1), aa1b = *(const floatx4*)(aam + ga1 + 4);
        floatx4 ww1a = *(const floatx4*)(gcw + ga1), ww1b = *(const floatx4*)(gcw + ga1 + 4);
        const int jj = k0 + 2 * kp, tt = jj >> 6, cc = jj & 63;
        const size_t gx0 = ((size_t)(b * NC + cc) * NT + tt) * DH + dg;
        const size_t gx1 = gx0 + (size_t)NT * DH;
        floatx4 x0a = *(const floatx4*)(hmat + gx0), x0b = *(const floatx4*)(hmat + gx0 + 4);
        floatx4 x1a = *(const floatx4*)(hmat + gx1), x1b = *(const floatx4*)(hmat + gx1 + 4);
        __syncthreads();
        short8 p0, p1;
#pragma unroll
        for (int e = 0; e < 4; ++e) {
            float v0 = aa0a[e]*ww0a[e]; v0 = v0>0.f?v0:0.f;
            float v1 = aa0b[e]*ww0b[e]; v1 = v1>0.f?v1:0.f;
            float v2 = aa1a[e]*ww1a[e]; v2 = v2>0.f?v2:0.f;
            float v3 = aa1b[e]*ww1b[e]; v3 = v3>0.f?v3:0.f;
            p0[e] = (short)f2bf(v0); p0[e+4] = (short)f2bf(v1);
            p1[e] = (short)f2bf(v2); p1[e+4] = (short)f2bf(v3);
        }
        *(short8*)&sA[ar * APAD + ac] = p0;
        *(short8*)&sA[(ar + 64) * APAD + ac] = p1;
#pragma unroll
        for (int e = 0; e < 4; ++e) {
            unsigned int pka = (unsigned int)f2bf(x0a[e]) | ((unsigned int)f2bf(x1a[e]) << 16);
            unsigned int pkb = (unsigned int)f2bf(x0b[e]) | ((unsigned int)f2bf(x1b[e]) << 16);
            sX[(dg + e) * XPAD + (kp ^ wkey)] = pka;
            sX[(dg + e + 4) * XPAD + (kp ^ wkey)] = pkb;
        }
        __syncthreads();
        short8 afrag[4], bfrag[4];
#pragma unroll
        for (int mi = 0; mi < 4; ++mi)
            afrag[mi] = *(const short8*)&sA[(wm + mi * 16 + l15) * APAD + q * 8];
#pragma unroll
        for (int ni = 0; ni < 4; ++ni) {
            const int row = wn + ni * 16 + l15;
            const int col = (q * 4) ^ (((row >> 3) & 3) << 2);
            bfrag[ni] = *(const short8*)(sX + row * XPAD + col);
        }
#pragma unroll
        for (int mi = 0; mi < 4; ++mi)
#pragma unroll
            for (int ni = 0; ni < 4; ++ni)
                acc[mi][ni] = __builtin_amdgcn_mfma_f32_16x16x32_bf16(
                    afrag[mi], bfrag[ni], acc[mi][ni], 0, 0, 0);
    }
#pragma unroll
    for (int mi = 0; mi < 4; ++mi) {
        const int ibase = i0 + wm + mi * 16 + q * 4;
#pragma unroll
        for (int ni = 0; ni < 4; ++ni) {
            const int d = wn + ni * 16 + l15;
#pragma unroll
            for (int r = 0; r < 4; ++r) {
                const int i = ibase + r;
                float v = acc[mi][ni][r] + gcb[(size_t)i * DH + d];
                v = v > 0.f ? v : 0.f;
                out[(((size_t)b * NS + (i & 63)) * NT + (i >> 6)) * DH + d] = v;
            }
        }
    }
}

extern "C" void kernel_launch(void* const* d_in, const int* in_sizes, int n_in,
                              void* d_out, int out_size, void* d_ws, size_t ws_size,
                              hipStream_t stream) {
    const float* h   = (const float*)d_in[0];
    const float* aam = (const float*)d_in[2];
    const float* gcw = (const float*)d_in[3];
    const float* gcb = (const float*)d_in[4];
    float* out = (float*)d_out;

    const size_t A_BYTES  = (size_t)MDIM * KDIM * 2;            // 33.55 MB
    const size_t XT_BYTES = (size_t)BATCH * DH * KDIM * 2;      // 16.78 MB

    if (ws_size >= A_BYTES + XT_BYTES) {
        unsigned short* A2 = (unsigned short*)d_ws;
        unsigned short* XT = (unsigned short*)((char*)d_ws + A_BYTES);
        prep<<<dim3(2048 + BATCH * NT), 256, 0, stream>>>(aam, gcw, h, A2, XT);
        gemm<<<dim3((MDIM / TM) * BATCH), 256, 0, stream>>>(A2, XT, gcb, out);
    } else {
        gcn_fused<<<dim3((MDIM / TM) * BATCH), 256, 0, stream>>>(h, aam, gcw, gcb, out);
    }
}

// Round 7
// 290.040 us; speedup vs baseline: 1.0423x; 1.0423x over previous
//
#include <hip/hip_runtime.h>

// GCNFast: out[b,s,t,d] = relu( sum_j relu(AA[i%64,j%64]*GCW[i,j]) * X[j,b,d] + GCB[i,d] )
// prep: A2 = relu(AA*GCW) bf16 fragment-major [mp][kc][row][8] + XT bf16 [b*128+d][j].
// gemm: 128x128 tile, 16x16x32 MFMA. Prefetch-distance-1 on BOTH operands:
//   - af tile i+1 -> ping-pong VGPR sets during tile i (retired by next barrier's vmcnt(0))
//   - X tile i+1 -> alternate LDS buffer via global_load_lds (R4 swizzle, 0 conflicts)
// MFMA never waits on same-iteration VMEM (R6 lesson: vmcnt is FIFO — a wait on a late
// load drains every earlier outstanding op, including prefetch DMAs).

#define NC 64
#define NS 64
#define NT 64
#define DH 128
#define BATCH 16
#define MDIM 4096
#define KDIM 4096
#define TM 128
#define TK 64

typedef __attribute__((ext_vector_type(8))) short short8;
typedef __attribute__((ext_vector_type(4))) float floatx4;

__device__ __forceinline__ unsigned short f2bf(float f) {
    union { float f; unsigned int i; } v; v.f = f;
    return (unsigned short)((v.i + 0x7fffu + ((v.i >> 16) & 1u)) >> 16);
}
__device__ __forceinline__ void async16(const void* g, void* l) {
    __builtin_amdgcn_global_load_lds(
        (const __attribute__((address_space(1))) void*)g,
        (__attribute__((address_space(3))) void*)l, 16, 0, 0);
}

// ---- prep: A2 fragment-major + XT (verified R6) ----
__global__ __launch_bounds__(256)
void prep(const float* __restrict__ aam, const float* __restrict__ gcw,
          const float* __restrict__ hmat,
          unsigned short* __restrict__ A2, unsigned short* __restrict__ XT)
{
    const int bid = blockIdx.x;
    if (bid < 2048) {
        const int mpb = bid >> 6;
        const int kcg = bid & 63;
        const int r   = threadIdx.x >> 1;
        const int kh  = threadIdx.x & 1;
        const size_t gbase = (size_t)(mpb * 128 + r) * KDIM + kcg * 64 + kh * 32;
        floatx4 a[8], w[8];
#pragma unroll
        for (int c = 0; c < 8; ++c) {
            a[c] = *(const floatx4*)(aam + gbase + c * 4);
            w[c] = *(const floatx4*)(gcw + gbase + c * 4);
        }
#pragma unroll
        for (int kc4 = 0; kc4 < 4; ++kc4) {
            short8 p;
#pragma unroll
            for (int e = 0; e < 4; ++e) {
                float v0 = a[kc4 * 2][e] * w[kc4 * 2][e];         v0 = v0 > 0.f ? v0 : 0.f;
                float v1 = a[kc4 * 2 + 1][e] * w[kc4 * 2 + 1][e]; v1 = v1 > 0.f ? v1 : 0.f;
                p[e]     = (short)f2bf(v0);
                p[e + 4] = (short)f2bf(v1);
            }
            const int kc = kcg * 8 + kh * 4 + kc4;
            *(short8*)(A2 + ((size_t)(mpb * 512 + kc) * 128 + r) * 8) = p;
        }
    } else {
        const int xb = bid - 2048;
        const int b = xb >> 6;
        const int t = xb & 63;
        const int d = threadIdx.x & 127;
        const int half = threadIdx.x >> 7;
#pragma unroll
        for (int cc = 0; cc < 4; ++cc) {
            const int c0 = half * 32 + cc * 8;
            short8 p;
#pragma unroll
            for (int e = 0; e < 8; ++e) {
                float v = hmat[(((size_t)b * NC + (c0 + e)) * NT + t) * DH + d];
                p[e] = (short)f2bf(v);
            }
            *(short8*)(XT + ((size_t)(b * DH + d)) * KDIM + t * 64 + c0) = p;
        }
    }
}

// ---- GEMM: distance-1 prefetch, ping-pong af regs + double-buffered sX ----
__global__ __launch_bounds__(256, 2)
void gemm(const unsigned short* __restrict__ A2,
          const unsigned short* __restrict__ XT,
          const float* __restrict__ gcb,
          float* __restrict__ out)
{
    __shared__ short sX[2][TM * TK];   // two 16 KB X^T tiles, chunk-swizzled

    const int tid = threadIdx.x;
    const int bid = blockIdx.x;
    const int mp  = (bid & 7) * 4 + (bid >> 7);   // m-panel 0..31 (XCD swizzle)
    const int b   = (bid >> 3) & 15;
    const int i0  = mp * TM;

    const int lane = tid & 63;
    const int w    = tid >> 6;
    const int wm = (w >> 1) * 64;
    const int wn = (w & 1) * 64;
    const int l15 = lane & 15;
    const int q   = lane >> 4;

    const int srow = lane >> 3;     // staging row within 8-row group
    const int schk = lane & 7;      // staging 16B chunk within 128B row
    const int lrow = (w * 8) * TK;  // LDS dst base row offset for this wave

    const unsigned short* ap =
        A2 + ((size_t)mp * 512 + q) * 1024 + (size_t)(wm + l15) * 8;

    floatx4 acc[4][4];
#pragma unroll
    for (int mi = 0; mi < 4; ++mi)
#pragma unroll
        for (int ni = 0; ni < 4; ++ni)
            acc[mi][ni] = (floatx4){0.f, 0.f, 0.f, 0.f};

    short8 af0[2][4], af1[2][4];

    // prologue: DMA tile 0 -> buf 0, af tile 0 -> af0
#pragma unroll
    for (int is = 0; is < 4; ++is) {
        const int r  = w * 8 + is * 32 + srow;
        const int kk = (schk ^ (r & 7)) << 3;
        async16(XT + (size_t)(b * DH + r) * KDIM + kk, &sX[0][lrow + is * 32 * TK]);
    }
#pragma unroll
    for (int h = 0; h < 2; ++h)
#pragma unroll
        for (int mi = 0; mi < 4; ++mi)
            af0[h][mi] = *(const short8*)(ap + h * 4096 + mi * 128);

    for (int k0 = 0; k0 < KDIM; k0 += 2 * TK) {
        // ---- phase A: consume tile i (buf0/af0), prefetch tile i+1 (buf1/af1) ----
        __syncthreads();   // drains vmcnt(0): buf0 DMA + af0 loads retired
        {
            const int kn = k0 + TK;   // always < KDIM here
#pragma unroll
            for (int is = 0; is < 4; ++is) {
                const int r  = w * 8 + is * 32 + srow;
                const int kk = kn + ((schk ^ (r & 7)) << 3);
                async16(XT + (size_t)(b * DH + r) * KDIM + kk, &sX[1][lrow + is * 32 * TK]);
            }
            const unsigned short* apn = ap + (size_t)kn * 128;
#pragma unroll
            for (int h = 0; h < 2; ++h)
#pragma unroll
                for (int mi = 0; mi < 4; ++mi)
                    af1[h][mi] = *(const short8*)(apn + h * 4096 + mi * 128);
        }
        {
            short8 bf[2][4];
#pragma unroll
            for (int h = 0; h < 2; ++h)
#pragma unroll
                for (int ni = 0; ni < 4; ++ni) {
                    const int row = wn + ni * 16 + l15;
                    bf[h][ni] = *(const short8*)&sX[0][row * TK + (((h * 4 + q) ^ (l15 & 7)) << 3)];
                }
#pragma unroll
            for (int h = 0; h < 2; ++h)
#pragma unroll
                for (int mi = 0; mi < 4; ++mi)
#pragma unroll
                    for (int ni = 0; ni < 4; ++ni)
                        acc[mi][ni] = __builtin_amdgcn_mfma_f32_16x16x32_bf16(
                            af0[h][mi], bf[h][ni], acc[mi][ni], 0, 0, 0);
        }

        // ---- phase B: consume tile i+1 (buf1/af1), prefetch tile i+2 (buf0/af0) ----
        __syncthreads();   // drains buf1 DMA + af1 loads
        if (k0 + 2 * TK < KDIM) {
            const int kn = k0 + 2 * TK;
#pragma unroll
            for (int is = 0; is < 4; ++is) {
                const int r  = w * 8 + is * 32 + srow;
                const int kk = kn + ((schk ^ (r & 7)) << 3);
                async16(XT + (size_t)(b * DH + r) * KDIM + kk, &sX[0][lrow + is * 32 * TK]);
            }
            const unsigned short* apn = ap + (size_t)kn * 128;
#pragma unroll
            for (int h = 0; h < 2; ++h)
#pragma unroll
                for (int mi = 0; mi < 4; ++mi)
                    af0[h][mi] = *(const short8*)(apn + h * 4096 + mi * 128);
        }
        {
            short8 bf[2][4];
#pragma unroll
            for (int h = 0; h < 2; ++h)
#pragma unroll
                for (int ni = 0; ni < 4; ++ni) {
                    const int row = wn + ni * 16 + l15;
                    bf[h][ni] = *(const short8*)&sX[1][row * TK + (((h * 4 + q) ^ (l15 & 7)) << 3)];
                }
#pragma unroll
            for (int h = 0; h < 2; ++h)
#pragma unroll
                for (int mi = 0; mi < 4; ++mi)
#pragma unroll
                    for (int ni = 0; ni < 4; ++ni)
                        acc[mi][ni] = __builtin_amdgcn_mfma_f32_16x16x32_bf16(
                            af1[h][mi], bf[h][ni], acc[mi][ni], 0, 0, 0);
        }
    }

    // epilogue: + GCB, relu, permuted store out[b, s=i&63, t=i>>6, d]
#pragma unroll
    for (int mi = 0; mi < 4; ++mi) {
        const int ibase = i0 + wm + mi * 16 + q * 4;   // C/D: row = q*4 + reg
#pragma unroll
        for (int ni = 0; ni < 4; ++ni) {
            const int d = wn + ni * 16 + l15;          // C/D: col = lane&15
#pragma unroll
            for (int r = 0; r < 4; ++r) {
                const int i = ibase + r;
                float v = acc[mi][ni][r] + gcb[(size_t)i * DH + d];
                v = v > 0.f ? v : 0.f;
                out[(((size_t)b * NS + (i & 63)) * NT + (i >> 6)) * DH + d] = v;
            }
        }
    }
}

// ---- fallback: fused kernel (used only if ws too small) ----
#define APAD 40
#define XPAD 20
__global__ __launch_bounds__(256, 2)
void gcn_fused(const float* __restrict__ hmat, const float* __restrict__ aam,
               const float* __restrict__ gcw, const float* __restrict__ gcb,
               float* __restrict__ out)
{
    __shared__ short sA[TM * APAD];
    __shared__ unsigned int sX[DH * XPAD];
    const int tid = threadIdx.x;
    const int bid = blockIdx.x;
    const int mp  = (bid & 7) * 4 + (bid >> 7);
    const int b   = (bid >> 3) & 15;
    const int i0  = mp * TM;
    const int lane = tid & 63;
    const int wm = ((tid >> 6) >> 1) * 64;
    const int wn = ((tid >> 6) & 1) * 64;
    const int l15 = lane & 15;
    const int q   = lane >> 4;
    floatx4 acc[4][4];
#pragma unroll
    for (int mi = 0; mi < 4; ++mi)
#pragma unroll
        for (int ni = 0; ni < 4; ++ni) acc[mi][ni] = (floatx4){0.f,0.f,0.f,0.f};
    const int ar = tid >> 2, ac = (tid & 3) << 3;
    const int kp = tid >> 4, dg = (tid & 15) << 3;
    const int wkey = (tid & 3) << 2;
    for (int k0 = 0; k0 < KDIM; k0 += 32) {
        const size_t ga0 = (size_t)(i0 + ar) * KDIM + (k0 + ac);
        const size_t ga1 = ga0 + (size_t)64 * KDIM;
        floatx4 aa0a = *(const floatx4*)(aam + ga0), aa0b = *(const floatx4*)(aam + ga0 + 4);
        floatx4 ww0a = *(const floatx4*)(gcw + ga0), ww0b = *(const floatx4*)(gcw + ga0 + 4);
        floatx4 aa1a = *(const floatx4*)(aam + ga1), aa1b = *(const floatx4*)(aam + ga1 + 4);
        floatx4 ww1a = *(const floatx4*)(gcw + ga1), ww1b = *(const floatx4*)(gcw + ga1 + 4);
        const int jj = k0 + 2 * kp, tt = jj >> 6, cc = jj & 63;
        const size_t gx0 = ((size_t)(b * NC + cc) * NT + tt) * DH + dg;
        const size_t gx1 = gx0 + (size_t)NT * DH;
        floatx4 x0a = *(const floatx4*)(hmat + gx0), x0b = *(const floatx4*)(hmat + gx0 + 4);
        floatx4 x1a = *(const floatx4*)(hmat + gx1), x1b = *(const floatx4*)(hmat + gx1 + 4);
        __syncthreads();
        short8 p0, p1;
#pragma unroll
        for (int e = 0; e < 4; ++e) {
            float v0 = aa0a[e]*ww0a[e]; v0 = v0>0.f?v0:0.f;
            float v1 = aa0b[e]*ww0b[e]; v1 = v1>0.f?v1:0.f;
            float v2 = aa1a[e]*ww1a[e]; v2 = v2>0.f?v2:0.f;
            float v3 = aa1b[e]*ww1b[e]; v3 = v3>0.f?v3:0.f;
            p0[e] = (short)f2bf(v0); p0[e+4] = (short)f2bf(v1);
            p1[e] = (short)f2bf(v2); p1[e+4] = (short)f2bf(v3);
        }
        *(short8*)&sA[ar * APAD + ac] = p0;
        *(short8*)&sA[(ar + 64) * APAD + ac] = p1;
#pragma unroll
        for (int e = 0; e < 4; ++e) {
            unsigned int pka = (unsigned int)f2bf(x0a[e]) | ((unsigned int)f2bf(x1a[e]) << 16);
            unsigned int pkb = (unsigned int)f2bf(x0b[e]) | ((unsigned int)f2bf(x1b[e]) << 16);
            sX[(dg + e) * XPAD + (kp ^ wkey)] = pka;
            sX[(dg + e + 4) * XPAD + (kp ^ wkey)] = pkb;
        }
        __syncthreads();
        short8 afrag[4], bfrag[4];
#pragma unroll
        for (int mi = 0; mi < 4; ++mi)
            afrag[mi] = *(const short8*)&sA[(wm + mi * 16 + l15) * APAD + q * 8];
#pragma unroll
        for (int ni = 0; ni < 4; ++ni) {
            const int row = wn + ni * 16 + l15;
            const int col = (q * 4) ^ (((row >> 3) & 3) << 2);
            bfrag[ni] = *(const short8*)(sX + row * XPAD + col);
        }
#pragma unroll
        for (int mi = 0; mi < 4; ++mi)
#pragma unroll
            for (int ni = 0; ni < 4; ++ni)
                acc[mi][ni] = __builtin_amdgcn_mfma_f32_16x16x32_bf16(
                    afrag[mi], bfrag[ni], acc[mi][ni], 0, 0, 0);
    }
#pragma unroll
    for (int mi = 0; mi < 4; ++mi) {
        const int ibase = i0 + wm + mi * 16 + q * 4;
#pragma unroll
        for (int ni = 0; ni < 4; ++ni) {
            const int d = wn + ni * 16 + l15;
#pragma unroll
            for (int r = 0; r < 4; ++r) {
                const int i = ibase + r;
                float v = acc[mi][ni][r] + gcb[(size_t)i * DH + d];
                v = v > 0.f ? v : 0.f;
                out[(((size_t)b * NS + (i & 63)) * NT + (i >> 6)) * DH + d] = v;
            }
        }
    }
}

extern "C" void kernel_launch(void* const* d_in, const int* in_sizes, int n_in,
                              void* d_out, int out_size, void* d_ws, size_t ws_size,
                              hipStream_t stream) {
    const float* h   = (const float*)d_in[0];
    const float* aam = (const float*)d_in[2];
    const float* gcw = (const float*)d_in[3];
    const float* gcb = (const float*)d_in[4];
    float* out = (float*)d_out;

    const size_t A_BYTES  = (size_t)MDIM * KDIM * 2;            // 33.55 MB
    const size_t XT_BYTES = (size_t)BATCH * DH * KDIM * 2;      // 16.78 MB

    if (ws_size >= A_BYTES + XT_BYTES) {
        unsigned short* A2 = (unsigned short*)d_ws;
        unsigned short* XT = (unsigned short*)((char*)d_ws + A_BYTES);
        prep<<<dim3(2048 + BATCH * NT), 256, 0, stream>>>(aam, gcw, h, A2, XT);
        gemm<<<dim3((MDIM / TM) * BATCH), 256, 0, stream>>>(A2, XT, gcb, out);
    } else {
        gcn_fused<<<dim3((MDIM / TM) * BATCH), 256, 0, stream>>>(h, aam, gcw, gcb, out);
    }
}